// Round 3
// baseline (116.030 us; speedup 1.0000x reference)
//
#include <hip/hip_runtime.h>
#include <hip/hip_bf16.h>

// Problem constants (setup_inputs is fixed):
//   x: (B=16, T=2048, D=64) fp32, pred_len=720, k=16, low_freq=1
//   out: (16, 2768, 64) fp32
#define B_SZ 16
#define T_SZ 2048
#define D_SZ 64
#define M_SZ 1024          // complex FFT length (T/2)
#define K_SEL 16
#define TOUT 2768          // T + pred_len
#define TCHUNK 4           // tau rows per synth block
#define NCHUNK (TOUT / TCHUNK)   // 692

// ---------------------------------------------------------------------------
// Kernel A: per-(b,d) real FFT of length 2048 (as complex FFT of 1024 +
// unpack), magnitude top-16 selection, write (j, Re, Im) triples to ws.
// ---------------------------------------------------------------------------
__global__ __launch_bounds__(256) void fft_topk_kernel(
    const float* __restrict__ x,
    int* __restrict__ sel_j,     // (1024, 16)
    float* __restrict__ sel_re,  // (1024, 16)
    float* __restrict__ sel_im)  // (1024, 16)
{
    __shared__ float a_re[M_SZ], a_im[M_SZ];
    __shared__ float tw_re[M_SZ / 2], tw_im[M_SZ / 2];
    __shared__ float X_re[M_SZ], X_im[M_SZ];
    __shared__ float mag2[M_SZ];
    __shared__ float wmax[4];
    __shared__ int   warg[4];
    __shared__ int   sel_list[K_SEL];

    const int bd  = blockIdx.x;          // 0..1023
    const int b   = bd >> 6;
    const int d   = bd & 63;
    const int tid = threadIdx.x;

    // Twiddle table: tw[k] = e^{-2*pi*i*k/1024}. sinpif/cospif are sub-ulp.
    for (int k = tid; k < M_SZ / 2; k += 256) {
        float a = (float)k * (1.0f / 512.0f);   // k/512 exact
        tw_re[k] =  cospif(a);
        tw_im[k] = -sinpif(a);
    }

    // Load x[b, :, d] with even/odd packing, bit-reversed positions (DIT).
    const float* xb = x + (size_t)b * T_SZ * D_SZ + d;
    for (int m = tid; m < M_SZ; m += 256) {
        float xe = xb[(2 * m) * D_SZ];
        float xo = xb[(2 * m + 1) * D_SZ];
        int pos = __brev((unsigned)m) >> 22;    // 10-bit reversal
        a_re[pos] = xe;
        a_im[pos] = xo;
    }
    __syncthreads();

    // 10 radix-2 DIT stages; butterflies disjoint within a stage.
    for (int s = 0; s < 10; ++s) {
        #pragma unroll 2
        for (int q = tid; q < M_SZ / 2; q += 256) {
            int half = 1 << s;
            int pos  = q & (half - 1);
            int i0   = ((q >> s) << (s + 1)) + pos;
            int i1   = i0 + half;
            int twi  = pos << (9 - s);
            float wr = tw_re[twi], wi = tw_im[twi];
            float br = a_re[i1],  bi = a_im[i1];
            float tr = fmaf(wr, br, -wi * bi);
            float ti = fmaf(wr, bi,  wi * br);
            float ar = a_re[i0],  ai = a_im[i0];
            a_re[i0] = ar + tr;  a_im[i0] = ai + ti;
            a_re[i1] = ar - tr;  a_im[i1] = ai - ti;
        }
        __syncthreads();
    }

    // Real-FFT unpack: X[j] = E[j] + e^{-2pi i j/2048} * O[j], j = 1..1023.
    for (int j = tid; j < M_SZ; j += 256) {
        if (j == 0) {
            X_re[0] = 0.0f; X_im[0] = 0.0f; mag2[0] = -2.0f;  // excluded bin
            continue;
        }
        int jc = M_SZ - j;                       // 1..1023
        float zr = a_re[j],  zi = a_im[j];
        float cr = a_re[jc], ci = a_im[jc];
        float er = 0.5f * (zr + cr), ei = 0.5f * (zi - ci);
        float ur = zr - cr,  vv = zi + ci;       // Z[j]-conj(Z[jc]) = (ur, vv)
        float orr = 0.5f * vv, oii = -0.5f * ur; // * (-i/2)
        float a  = (float)j * (1.0f / 1024.0f);  // j/1024 exact
        float twr =  cospif(a);
        float twq = -sinpif(a);
        float xr = er + twr * orr - twq * oii;
        float xi = ei + twr * oii + twq * orr;
        X_re[j] = xr; X_im[j] = xi;
        mag2[j] = xr * xr + xi * xi;
    }
    __syncthreads();

    // Top-16 by mag2, lower index wins ties (matches lax.top_k).
    const int lane = tid & 63, wv = tid >> 6;
    for (int it = 0; it < K_SEL; ++it) {
        float bv = -1.0f; int bj = M_SZ;
        #pragma unroll
        for (int r = 0; r < 4; ++r) {
            int j = tid + 256 * r;     // j increasing => strict > keeps low j
            float v = mag2[j];
            if (v > bv) { bv = v; bj = j; }
        }
        #pragma unroll
        for (int off = 32; off; off >>= 1) {
            float ov = __shfl_xor(bv, off);
            int   oj = __shfl_xor(bj, off);
            if (ov > bv || (ov == bv && oj < bj)) { bv = ov; bj = oj; }
        }
        if (lane == 0) { wmax[wv] = bv; warg[wv] = bj; }
        __syncthreads();
        if (tid == 0) {
            float best = wmax[0]; int bidx = warg[0];
            #pragma unroll
            for (int w = 1; w < 4; ++w) {
                if (wmax[w] > best || (wmax[w] == best && warg[w] < bidx)) {
                    best = wmax[w]; bidx = warg[w];
                }
            }
            sel_list[it] = bidx;
            mag2[bidx] = -2.0f;
        }
        __syncthreads();
    }

    if (tid < K_SEL) {
        int j = sel_list[tid];
        sel_j [bd * K_SEL + tid] = j;
        sel_re[bd * K_SEL + tid] = X_re[j];
        sel_im[bd * K_SEL + tid] = X_im[j];
    }
}

// ---------------------------------------------------------------------------
// Kernel C: out[b,tau,d] = (1/1024) * sum_i ( Re_i*cos(2pi j_i tau/2048)
//                                            - Im_i*sin(2pi j_i tau/2048) )
// Exact phase reduction: (j*tau mod 2048)/2048 revolutions -> v_cos/v_sin.
// Block = 4 tau x 64 d  => coalesced 256B output rows.
// ---------------------------------------------------------------------------
__global__ __launch_bounds__(256) void synth_kernel(
    const int*   __restrict__ sel_j,
    const float* __restrict__ sel_re,
    const float* __restrict__ sel_im,
    float* __restrict__ out)
{
    __shared__ int   js [K_SEL][65];   // [q][d], padded: conflict-free reads
    __shared__ float res[K_SEL][65];
    __shared__ float ims[K_SEL][65];

    const int bid   = blockIdx.x;          // b * NCHUNK + chunk
    const int b     = bid / NCHUNK;
    const int chunk = bid - b * NCHUNK;
    const int tid   = threadIdx.x;

    // Coalesced load of this b's 64 x 16 selection triples.
    for (int i = tid; i < D_SZ * K_SEL; i += 256) {
        int d = i >> 4, q = i & 15;
        int g = (b * D_SZ + d) * K_SEL + q;
        js [q][d] = sel_j [g];
        res[q][d] = sel_re[g];
        ims[q][d] = sel_im[g];
    }
    __syncthreads();

    const int d   = tid & 63;
    const int tau = chunk * TCHUNK + (tid >> 6);

    float acc = 0.0f;
    #pragma unroll
    for (int q = 0; q < K_SEL; ++q) {
        int   j  = js[q][d];
        int   ph = (j * tau) & (T_SZ - 1);           // exact mod 2048
        float r  = (float)ph * (1.0f / (float)T_SZ); // exact: /2^11
        float c  = __builtin_amdgcn_cosf(r);         // cos(2*pi*r)
        float s  = __builtin_amdgcn_sinf(r);         // sin(2*pi*r)
        acc = fmaf(res[q][d], c, acc);
        acc = fmaf(-ims[q][d], s, acc);
    }
    out[((size_t)b * TOUT + tau) * D_SZ + d] = acc * (1.0f / 1024.0f);
}

// ---------------------------------------------------------------------------
extern "C" void kernel_launch(void* const* d_in, const int* in_sizes, int n_in,
                              void* d_out, int out_size, void* d_ws, size_t ws_size,
                              hipStream_t stream) {
    const float* x = (const float*)d_in[0];

    // ws layout: sel_j (64KB) | sel_re (64KB) | sel_im (64KB)
    int*   sel_j  = (int*)d_ws;
    float* sel_re = (float*)((char*)d_ws + (size_t)B_SZ * D_SZ * K_SEL * 4);
    float* sel_im = (float*)((char*)d_ws + (size_t)2 * B_SZ * D_SZ * K_SEL * 4);

    fft_topk_kernel<<<dim3(B_SZ * D_SZ), dim3(256), 0, stream>>>(
        x, sel_j, sel_re, sel_im);

    synth_kernel<<<dim3(B_SZ * NCHUNK), dim3(256), 0, stream>>>(
        sel_j, sel_re, sel_im, (float*)d_out);
}